// Round 11
// baseline (34.548 us; speedup 1.0000x reference)
//
#include <hip/hip_runtime.h>
#include <hip/hip_bf16.h>

#define BB 4
#define NTOK 2048
#define E 96
#define NH 6
#define E3 288
#define MSZ 1536           // 6*16*16 floats per batch
#define SCALE 0.25f        // D^-0.5

typedef __attribute__((ext_vector_type(8))) short bf16x8;
typedef __attribute__((ext_vector_type(4))) float f32x4;

__device__ __forceinline__ short f2bf(float f) {
    __hip_bfloat16 h = __float2bfloat16(f);
    return __builtin_bit_cast(short, h);
}

// One fused kernel: 256 blocks (1/CU, all co-resident), 256 threads.
// A: kv = x@[Wk|Wv]+b (MFMA) -> M_h partial (MFMA) -> f32 atomics into Mg[b]
//    -> threadfence -> cnt[b]++.
// B: q = x@Wq+b (MFMA), Wff restage (overlaps M propagation).
// C: lane-0 RELAXED spin (s_sleep) until cnt[b]==64; relaxed-agent Mg loads;
//    t2 = q.BD(SCALE*M) (f32 VALU); out = t2@Wff+bff (MFMA).
__global__ __launch_bounds__(256) void k_all(const float* __restrict__ x,
                                             const float* __restrict__ Wqkv,
                                             const float* __restrict__ bqkv,
                                             const float* __restrict__ Wff,
                                             const float* __restrict__ bff,
                                             float* __restrict__ Mg,
                                             unsigned int* __restrict__ cnt,
                                             float* __restrict__ out) {
    const int L = ((blockIdx.x & 7) << 5) | (blockIdx.x >> 3);   // XCD-chunked
    const int b = L >> 6, tile = L & 63;
    const int n0 = tile * 32;
    const int t = threadIdx.x;

    __shared__ short xb[32 * 104];     // x tile bf16 [n][e]
    __shared__ short wkvT[192 * 104];  // [Wk|Wv]^T bf16 [c][e]
    __shared__ short kvn[192 * 40];    // kv^T bf16 [feat][n]
    __shared__ short wT[96 * 104];     // Wq^T then Wff^T bf16 [c][e]
    __shared__ float qs[32 * 100];     // q f32 [n][col]
    __shared__ float Ms2[NH * 320];    // SCALE*M, [h][d2*20 + d1]
    __shared__ short t2b[32 * 104];    // t2 bf16 [n][e]

    { // stage x -> bf16
        const float4* src = (const float4*)(x + ((size_t)b * NTOK + n0) * E);
        for (int f = t; f < 768; f += 256) {
            float4 v = src[f];
            int r = f / 24, c4 = (f % 24) * 4;
            short4 s = { f2bf(v.x), f2bf(v.y), f2bf(v.z), f2bf(v.w) };
            *(short4*)&xb[r * 104 + c4] = s;
        }
    }
    { // stage W[k|v]^T -> bf16
        for (int f = t; f < 2304; f += 256) {
            int ep = f / 48, cq = (f % 48) * 4;
            const float4 a = *(const float4*)(Wqkv + (size_t)(2 * ep) * E3 + E + cq);
            const float4 c = *(const float4*)(Wqkv + (size_t)(2 * ep + 1) * E3 + E + cq);
            *(short2*)&wkvT[(cq + 0) * 104 + 2 * ep] = make_short2(f2bf(a.x), f2bf(c.x));
            *(short2*)&wkvT[(cq + 1) * 104 + 2 * ep] = make_short2(f2bf(a.y), f2bf(c.y));
            *(short2*)&wkvT[(cq + 2) * 104 + 2 * ep] = make_short2(f2bf(a.z), f2bf(c.z));
            *(short2*)&wkvT[(cq + 3) * 104 + 2 * ep] = make_short2(f2bf(a.w), f2bf(c.w));
        }
    }
    { // stage Wq^T -> bf16
        for (int f = t; f < 1152; f += 256) {
            int ep = f / 24, cq = (f % 24) * 4;
            const float4 a = *(const float4*)(Wqkv + (size_t)(2 * ep) * E3 + cq);
            const float4 c = *(const float4*)(Wqkv + (size_t)(2 * ep + 1) * E3 + cq);
            *(short2*)&wT[(cq + 0) * 104 + 2 * ep] = make_short2(f2bf(a.x), f2bf(c.x));
            *(short2*)&wT[(cq + 1) * 104 + 2 * ep] = make_short2(f2bf(a.y), f2bf(c.y));
            *(short2*)&wT[(cq + 2) * 104 + 2 * ep] = make_short2(f2bf(a.z), f2bf(c.z));
            *(short2*)&wT[(cq + 3) * 104 + 2 * ep] = make_short2(f2bf(a.w), f2bf(c.w));
        }
    }
    __syncthreads();

    const int w = t >> 6, lane = t & 63;
    const int lr = lane & 15, kg = lane >> 4;
    const int rhalf = w & 1;
    const int nr = rhalf * 16 + kg * 4;

    { // kv MFMA: wave -> 6 C-tiles (16x16) x 3 K-steps; cols 96*(w>>1)
        const int chalf = w >> 1;
        f32x4 acc[6];
#pragma unroll
        for (int j = 0; j < 6; j++) acc[j] = (f32x4){0.f, 0.f, 0.f, 0.f};
#pragma unroll
        for (int ks = 0; ks < 3; ks++) {
            const bf16x8 af = *(const bf16x8*)&xb[(rhalf * 16 + lr) * 104 + ks * 32 + kg * 8];
#pragma unroll
            for (int j = 0; j < 6; j++) {
                const bf16x8 bf = *(const bf16x8*)&wkvT[(chalf * 96 + j * 16 + lr) * 104 + ks * 32 + kg * 8];
                acc[j] = __builtin_amdgcn_mfma_f32_16x16x32_bf16(af, bf, acc[j], 0, 0, 0);
            }
        }
#pragma unroll
        for (int j = 0; j < 6; j++) {
            const int cg = chalf * 96 + j * 16 + lr;
            const float bias = bqkv[E + cg];
            short4 s = { f2bf(acc[j][0] + bias), f2bf(acc[j][1] + bias),
                         f2bf(acc[j][2] + bias), f2bf(acc[j][3] + bias) };
            *(short4*)&kvn[cg * 40 + nr] = s;
        }
    }
    __syncthreads();

    { // M phase: head h -> one MFMA (K=32 tokens), f32 atomics into Mg[b]
        for (int h = w; h < NH; h += 4) {
            const bf16x8 ka = *(const bf16x8*)&kvn[(h * 16 + lr) * 40 + kg * 8];
            const bf16x8 vb = *(const bf16x8*)&kvn[(96 + h * 16 + lr) * 40 + kg * 8];
            f32x4 mc = (f32x4){0.f, 0.f, 0.f, 0.f};
            mc = __builtin_amdgcn_mfma_f32_16x16x32_bf16(ka, vb, mc, 0, 0, 0);
            float* base = &Mg[b * MSZ + h * 256];          // [d1][d2], d1=kg*4+i, d2=lr
            unsafeAtomicAdd(base + (kg * 4 + 0) * 16 + lr, mc[0]);
            unsafeAtomicAdd(base + (kg * 4 + 1) * 16 + lr, mc[1]);
            unsafeAtomicAdd(base + (kg * 4 + 2) * 16 + lr, mc[2]);
            unsafeAtomicAdd(base + (kg * 4 + 3) * 16 + lr, mc[3]);
        }
    }
    __threadfence();
    __syncthreads();
    if (t == 0) atomicAdd(&cnt[b], 1u);

    { // q MFMA: wave -> 3 C-tiles x 3 K-steps; +bias -> qs (f32)
        const int chalf = w >> 1;
        f32x4 acc[3];
#pragma unroll
        for (int j = 0; j < 3; j++) acc[j] = (f32x4){0.f, 0.f, 0.f, 0.f};
#pragma unroll
        for (int ks = 0; ks < 3; ks++) {
            const bf16x8 af = *(const bf16x8*)&xb[(rhalf * 16 + lr) * 104 + ks * 32 + kg * 8];
#pragma unroll
            for (int j = 0; j < 3; j++) {
                const bf16x8 bf = *(const bf16x8*)&wT[(chalf * 48 + j * 16 + lr) * 104 + ks * 32 + kg * 8];
                acc[j] = __builtin_amdgcn_mfma_f32_16x16x32_bf16(af, bf, acc[j], 0, 0, 0);
            }
        }
#pragma unroll
        for (int j = 0; j < 3; j++) {
            const int col = chalf * 48 + j * 16 + lr;
            const float bq = bqkv[col];
            qs[(nr + 0) * 100 + col] = acc[j][0] + bq;
            qs[(nr + 1) * 100 + col] = acc[j][1] + bq;
            qs[(nr + 2) * 100 + col] = acc[j][2] + bq;
            qs[(nr + 3) * 100 + col] = acc[j][3] + bq;
        }
    }
    __syncthreads();

    { // restage wT <- Wff^T (overlaps M propagation / other blocks' phase A)
        for (int f = t; f < 1152; f += 256) {
            int ep = f / 24, cq = (f % 24) * 4;
            const float4 a = *(const float4*)(Wff + (size_t)(2 * ep) * E + cq);
            const float4 c = *(const float4*)(Wff + (size_t)(2 * ep + 1) * E + cq);
            *(short2*)&wT[(cq + 0) * 104 + 2 * ep] = make_short2(f2bf(a.x), f2bf(c.x));
            *(short2*)&wT[(cq + 1) * 104 + 2 * ep] = make_short2(f2bf(a.y), f2bf(c.y));
            *(short2*)&wT[(cq + 2) * 104 + 2 * ep] = make_short2(f2bf(a.z), f2bf(c.z));
            *(short2*)&wT[(cq + 3) * 104 + 2 * ep] = make_short2(f2bf(a.w), f2bf(c.w));
        }
    }
    // wait for all 64 tiles of this batch: RELAXED polls only (no invalidates)
    if (t == 0) {
        while (__hip_atomic_load(&cnt[b], __ATOMIC_RELAXED, __HIP_MEMORY_SCOPE_AGENT) < 64u)
            __builtin_amdgcn_s_sleep(8);
    }
    __syncthreads();

    { // load M from coherent point (relaxed agent), scale -> Ms2
#pragma unroll
        for (int i = 0; i < 6; i++) {
            const int o = t + i * 256;
            const int h = o >> 8, d1 = (o >> 4) & 15, d2 = o & 15;
            Ms2[h * 320 + d2 * 20 + d1] =
                SCALE * __hip_atomic_load(&Mg[b * MSZ + o], __ATOMIC_RELAXED, __HIP_MEMORY_SCOPE_AGENT);
        }
    }
    __syncthreads();

    { // t2 = q . BD(Ms2)  (f32 VALU) -> t2b bf16
        const int r = t >> 3, tc0 = (t & 7) * 12;
        const int h0 = tc0 >> 4, h1 = (tc0 + 11) >> 4;
        float4 qa[4], qb[4];
#pragma unroll
        for (int u = 0; u < 4; u++) {
            qa[u] = *(const float4*)&qs[r * 100 + h0 * 16 + u * 4];
            qb[u] = *(const float4*)&qs[r * 100 + h1 * 16 + u * 4];
        }
        float t2v[12];
#pragma unroll
        for (int j = 0; j < 12; j++) {
            const int c = tc0 + j, h = c >> 4, d2 = c & 15;
            const float4* mrow = (const float4*)&Ms2[h * 320 + d2 * 20];
            float v = 0.f;
#pragma unroll
            for (int u = 0; u < 4; u++) {
                const float4 qv = (h == h0) ? qa[u] : qb[u];
                const float4 mf = mrow[u];
                v += qv.x * mf.x + qv.y * mf.y + qv.z * mf.z + qv.w * mf.w;
            }
            t2v[j] = v;
        }
#pragma unroll
        for (int q3 = 0; q3 < 3; q3++) {
            short4 s = { f2bf(t2v[q3 * 4]), f2bf(t2v[q3 * 4 + 1]),
                         f2bf(t2v[q3 * 4 + 2]), f2bf(t2v[q3 * 4 + 3]) };
            *(short4*)&t2b[r * 104 + tc0 + q3 * 4] = s;
        }
    }
    __syncthreads();

    { // out MFMA: 3 C-tiles x 3 K-steps; +bff; f32 stores
        const int chalf = w >> 1;
        f32x4 acc[3];
#pragma unroll
        for (int j = 0; j < 3; j++) acc[j] = (f32x4){0.f, 0.f, 0.f, 0.f};
#pragma unroll
        for (int ks = 0; ks < 3; ks++) {
            const bf16x8 af = *(const bf16x8*)&t2b[(rhalf * 16 + lr) * 104 + ks * 32 + kg * 8];
#pragma unroll
            for (int j = 0; j < 3; j++) {
                const bf16x8 bf = *(const bf16x8*)&wT[(chalf * 48 + j * 16 + lr) * 104 + ks * 32 + kg * 8];
                acc[j] = __builtin_amdgcn_mfma_f32_16x16x32_bf16(af, bf, acc[j], 0, 0, 0);
            }
        }
        float* obase = out + ((size_t)b * NTOK + n0 + nr) * E;
#pragma unroll
        for (int j = 0; j < 3; j++) {
            const int col = chalf * 48 + j * 16 + lr;
            const float bv = bff[col];
            obase[0 * E + col] = acc[j][0] + bv;
            obase[1 * E + col] = acc[j][1] + bv;
            obase[2 * E + col] = acc[j][2] + bv;
            obase[3 * E + col] = acc[j][3] + bv;
        }
    }
}

extern "C" void kernel_launch(void* const* d_in, const int* in_sizes, int n_in,
                              void* d_out, int out_size, void* d_ws, size_t ws_size,
                              hipStream_t stream) {
    const float* x    = (const float*)d_in[0];
    const float* Wqkv = (const float*)d_in[1];
    const float* bqkv = (const float*)d_in[2];
    const float* Wff  = (const float*)d_in[3];
    const float* bff  = (const float*)d_in[4];
    float* out = (float*)d_out;
    float* Mg  = (float*)d_ws;                               // BB*MSZ f32
    unsigned int* cnt = (unsigned int*)(Mg + BB * MSZ);      // BB counters

    hipMemsetAsync(d_ws, 0, (size_t)BB * MSZ * sizeof(float) + BB * sizeof(unsigned int), stream);
    k_all<<<BB * 64, 256, 0, stream>>>(x, Wqkv, bqkv, Wff, bff, Mg, cnt, out);
}

// Round 15
// 18.927 us; speedup vs baseline: 1.8254x; 1.8254x over previous
//
#include <hip/hip_runtime.h>
#include <hip/hip_bf16.h>

#define BB 4
#define NTOK 2048
#define E 96
#define NH 6
#define E3 288
#define MSZ 1536           // 6*16*16 per (batch,tile) partial
#define SCALE 0.25f        // D^-0.5

typedef __attribute__((ext_vector_type(8))) short bf16x8;
typedef __attribute__((ext_vector_type(4))) float f32x4;

__device__ __forceinline__ short f2bf(float f) {
    __hip_bfloat16 h = __float2bfloat16(f);
    return __builtin_bit_cast(short, h);
}

// ---- K1 (512 thr): kv = x@[Wk|Wv]+bias (MFMA), M_h = K_h^T V_h (one MFMA
// ----               per head), bf16 partial store (no atomics, no memset)
__global__ __launch_bounds__(512) void k_kv(const float* __restrict__ x,
                                            const float* __restrict__ Wqkv,
                                            const float* __restrict__ bqkv,
                                            short* __restrict__ Mp) {
    const int L = ((blockIdx.x & 7) << 5) | (blockIdx.x >> 3);   // XCD-chunked
    const int b = L >> 6, tile = L & 63;
    const int n0 = tile * 32;
    const int t = threadIdx.x;
    __shared__ short xb[32 * 104];     // x tile bf16 [n][e]
    __shared__ short wkvT[192 * 104];  // [Wk|Wv]^T bf16 [c][e]
    __shared__ short kvn[192 * 40];    // kv^T bf16 [feat][n]

    { // stage x -> bf16
        const float4* src = (const float4*)(x + ((size_t)b * NTOK + n0) * E);
        for (int f = t; f < 768; f += 512) {
            float4 v = src[f];
            int r = f / 24, c4 = (f % 24) * 4;
            short4 s = { f2bf(v.x), f2bf(v.y), f2bf(v.z), f2bf(v.w) };
            *(short4*)&xb[r * 104 + c4] = s;
        }
    }
    { // stage W[k|v]^T -> bf16 (e-pairs -> short2 writes)
        for (int f = t; f < 2304; f += 512) {
            int ep = f / 48, cq = (f % 48) * 4;
            const float4 a = *(const float4*)(Wqkv + (size_t)(2 * ep) * E3 + E + cq);
            const float4 c = *(const float4*)(Wqkv + (size_t)(2 * ep + 1) * E3 + E + cq);
            *(short2*)&wkvT[(cq + 0) * 104 + 2 * ep] = make_short2(f2bf(a.x), f2bf(c.x));
            *(short2*)&wkvT[(cq + 1) * 104 + 2 * ep] = make_short2(f2bf(a.y), f2bf(c.y));
            *(short2*)&wkvT[(cq + 2) * 104 + 2 * ep] = make_short2(f2bf(a.z), f2bf(c.z));
            *(short2*)&wkvT[(cq + 3) * 104 + 2 * ep] = make_short2(f2bf(a.w), f2bf(c.w));
        }
    }
    __syncthreads();

    const int w = t >> 6, lane = t & 63;
    const int lr = lane & 15, kg = lane >> 4;
    const int rhalf = w & 1, cq4 = w >> 1;      // 8 waves = 2 rhalf x 4 col-quads
    const int nr = rhalf * 16 + kg * 4;

    { // kv MFMA: each wave 3 C-tiles (16x16) x 3 K-steps (48 cols per quad)
        f32x4 acc[3];
#pragma unroll
        for (int j = 0; j < 3; j++) acc[j] = (f32x4){0.f, 0.f, 0.f, 0.f};
#pragma unroll
        for (int ks = 0; ks < 3; ks++) {
            const bf16x8 af = *(const bf16x8*)&xb[(rhalf * 16 + lr) * 104 + ks * 32 + kg * 8];
#pragma unroll
            for (int j = 0; j < 3; j++) {
                const bf16x8 bf = *(const bf16x8*)&wkvT[(cq4 * 48 + j * 16 + lr) * 104 + ks * 32 + kg * 8];
                acc[j] = __builtin_amdgcn_mfma_f32_16x16x32_bf16(af, bf, acc[j], 0, 0, 0);
            }
        }
#pragma unroll
        for (int j = 0; j < 3; j++) {
            const int cg = cq4 * 48 + j * 16 + lr;
            const float bias = bqkv[E + cg];
            short4 s = { f2bf(acc[j][0] + bias), f2bf(acc[j][1] + bias),
                         f2bf(acc[j][2] + bias), f2bf(acc[j][3] + bias) };
            *(short4*)&kvn[cg * 40 + nr] = s;
        }
    }
    __syncthreads();

    { // M phase: wave w -> head w (w<6): one 16x16x32 MFMA, bf16 partial
        if (w < NH) {
            const int h = w;
            const bf16x8 ka = *(const bf16x8*)&kvn[(h * 16 + lr) * 40 + kg * 8];
            const bf16x8 vb = *(const bf16x8*)&kvn[(96 + h * 16 + lr) * 40 + kg * 8];
            f32x4 mc = (f32x4){0.f, 0.f, 0.f, 0.f};
            mc = __builtin_amdgcn_mfma_f32_16x16x32_bf16(ka, vb, mc, 0, 0, 0);
            short* mpt = Mp + (size_t)L * MSZ;
            short4 s = { f2bf(mc[0]), f2bf(mc[1]), f2bf(mc[2]), f2bf(mc[3]) };
            *(short4*)&mpt[h * 256 + lane * 4] = s;
        }
    }
}

// ---- K2 (512 thr): reduce M partials -> Ms2; q = x@Wq+bq (MFMA);
// ----               t2 = q.BD(SCALE*M) (f32 VALU); out = t2@Wff+bff (MFMA)
__global__ __launch_bounds__(512) void k_out(const float* __restrict__ x,
                                             const float* __restrict__ Wqkv,
                                             const float* __restrict__ bqkv,
                                             const float* __restrict__ Wff,
                                             const float* __restrict__ bff,
                                             const short* __restrict__ Mp,
                                             float* __restrict__ out) {
    const int L = ((blockIdx.x & 7) << 5) | (blockIdx.x >> 3);   // XCD-chunked
    const int b = L >> 6, tile = L & 63;
    const int n0 = tile * 32;
    const int t = threadIdx.x;
    __shared__ short xb[32 * 104];     // x tile bf16
    __shared__ short wT[96 * 104];     // Wq^T then Wff^T bf16 [c][e]
    __shared__ short t2b[32 * 104];    // t2 bf16 [n][e]
    __shared__ float qs[32 * 100];     // q f32 [n][col]
    __shared__ float Ms2[NH * 320];    // SCALE*M, [h][d2*20 + d1]

    { // stage x -> bf16
        const float4* src = (const float4*)(x + ((size_t)b * NTOK + n0) * E);
        for (int f = t; f < 768; f += 512) {
            float4 v = src[f];
            int r = f / 24, c4 = (f % 24) * 4;
            short4 s = { f2bf(v.x), f2bf(v.y), f2bf(v.z), f2bf(v.w) };
            *(short4*)&xb[r * 104 + c4] = s;
        }
    }
    { // stage Wq^T -> bf16
        for (int f = t; f < 1152; f += 512) {
            int ep = f / 24, cq = (f % 24) * 4;
            const float4 a = *(const float4*)(Wqkv + (size_t)(2 * ep) * E3 + cq);
            const float4 c = *(const float4*)(Wqkv + (size_t)(2 * ep + 1) * E3 + cq);
            *(short2*)&wT[(cq + 0) * 104 + 2 * ep] = make_short2(f2bf(a.x), f2bf(c.x));
            *(short2*)&wT[(cq + 1) * 104 + 2 * ep] = make_short2(f2bf(a.y), f2bf(c.y));
            *(short2*)&wT[(cq + 2) * 104 + 2 * ep] = make_short2(f2bf(a.z), f2bf(c.z));
            *(short2*)&wT[(cq + 3) * 104 + 2 * ep] = make_short2(f2bf(a.w), f2bf(c.w));
        }
    }
    { // reduce 64 bf16 partials -> Ms2 (threads 0..191, 8 elements each)
        if (t < 192) {
            float racc[8];
#pragma unroll
            for (int j = 0; j < 8; j++) racc[j] = 0.f;
            const short* mpb = Mp + (size_t)b * 64 * MSZ + t * 8;
#pragma unroll 8
            for (int tl = 0; tl < 64; ++tl) {
                const bf16x8 v = *(const bf16x8*)(mpb + (size_t)tl * MSZ);
#pragma unroll
                for (int j = 0; j < 8; j++)
                    racc[j] += __uint_as_float(((unsigned)(unsigned short)v[j]) << 16);
            }
#pragma unroll
            for (int j = 0; j < 8; j++) {
                const int o = t * 8 + j;
                const int h = o >> 8, kg = (o >> 6) & 3, lr = (o >> 2) & 15, i = o & 3;
                Ms2[h * 320 + lr * 20 + kg * 4 + i] = SCALE * racc[j];
            }
        }
    }
    __syncthreads();

    const int w = t >> 6, lane = t & 63;
    const int lr = lane & 15, kg = lane >> 4;

    { // q MFMA: 12 tasks (rhalf x 6 col-tiles) over 8 waves; +bias -> qs (f32)
#pragma unroll
        for (int rep = 0; rep < 2; rep++) {
            const int T = w + rep * 8;
            if (T < 12) {
                const int rhalf = T & 1, jt = T >> 1;
                const int nr = rhalf * 16 + kg * 4;
                f32x4 acc = (f32x4){0.f, 0.f, 0.f, 0.f};
#pragma unroll
                for (int ks = 0; ks < 3; ks++) {
                    const bf16x8 af = *(const bf16x8*)&xb[(rhalf * 16 + lr) * 104 + ks * 32 + kg * 8];
                    const bf16x8 bf = *(const bf16x8*)&wT[(jt * 16 + lr) * 104 + ks * 32 + kg * 8];
                    acc = __builtin_amdgcn_mfma_f32_16x16x32_bf16(af, bf, acc, 0, 0, 0);
                }
                const int col = jt * 16 + lr;
                const float bq = bqkv[col];
                qs[(nr + 0) * 100 + col] = acc[0] + bq;
                qs[(nr + 1) * 100 + col] = acc[1] + bq;
                qs[(nr + 2) * 100 + col] = acc[2] + bq;
                qs[(nr + 3) * 100 + col] = acc[3] + bq;
            }
        }
    }
    __syncthreads();

    { // restage wT <- Wff^T (bf16)
        for (int f = t; f < 1152; f += 512) {
            int ep = f / 24, cq = (f % 24) * 4;
            const float4 a = *(const float4*)(Wff + (size_t)(2 * ep) * E + cq);
            const float4 c = *(const float4*)(Wff + (size_t)(2 * ep + 1) * E + cq);
            *(short2*)&wT[(cq + 0) * 104 + 2 * ep] = make_short2(f2bf(a.x), f2bf(c.x));
            *(short2*)&wT[(cq + 1) * 104 + 2 * ep] = make_short2(f2bf(a.y), f2bf(c.y));
            *(short2*)&wT[(cq + 2) * 104 + 2 * ep] = make_short2(f2bf(a.z), f2bf(c.z));
            *(short2*)&wT[(cq + 3) * 104 + 2 * ep] = make_short2(f2bf(a.w), f2bf(c.w));
        }
    }
    { // t2 = q . BD(Ms2) on threads < 256 (f32 VALU) -> t2b bf16
        if (t < 256) {
            const int r = t >> 3, tc0 = (t & 7) * 12;
            const int h0 = tc0 >> 4, h1 = (tc0 + 11) >> 4;
            float4 qa[4], qb[4];
#pragma unroll
            for (int u = 0; u < 4; u++) {
                qa[u] = *(const float4*)&qs[r * 100 + h0 * 16 + u * 4];
                qb[u] = *(const float4*)&qs[r * 100 + h1 * 16 + u * 4];
            }
            float t2v[12];
#pragma unroll
            for (int j = 0; j < 12; j++) {
                const int c = tc0 + j, h = c >> 4, d2 = c & 15;
                const float4* mrow = (const float4*)&Ms2[h * 320 + d2 * 20];
                float v = 0.f;
#pragma unroll
                for (int u = 0; u < 4; u++) {
                    const float4 qv = (h == h0) ? qa[u] : qb[u];
                    const float4 mf = mrow[u];
                    v += qv.x * mf.x + qv.y * mf.y + qv.z * mf.z + qv.w * mf.w;
                }
                t2v[j] = v;
            }
#pragma unroll
            for (int q3 = 0; q3 < 3; q3++) {
                short4 s = { f2bf(t2v[q3 * 4]), f2bf(t2v[q3 * 4 + 1]),
                             f2bf(t2v[q3 * 4 + 2]), f2bf(t2v[q3 * 4 + 3]) };
                *(short4*)&t2b[r * 104 + tc0 + q3 * 4] = s;
            }
        }
    }
    __syncthreads();

    { // out MFMA: 12 tasks over 8 waves; +bff; f32 stores
#pragma unroll
        for (int rep = 0; rep < 2; rep++) {
            const int T = w + rep * 8;
            if (T < 12) {
                const int rhalf = T & 1, jt = T >> 1;
                const int nr = rhalf * 16 + kg * 4;
                f32x4 acc = (f32x4){0.f, 0.f, 0.f, 0.f};
#pragma unroll
                for (int ks = 0; ks < 3; ks++) {
                    const bf16x8 af = *(const bf16x8*)&t2b[(rhalf * 16 + lr) * 104 + ks * 32 + kg * 8];
                    const bf16x8 bf = *(const bf16x8*)&wT[(jt * 16 + lr) * 104 + ks * 32 + kg * 8];
                    acc = __builtin_amdgcn_mfma_f32_16x16x32_bf16(af, bf, acc, 0, 0, 0);
                }
                const int col = jt * 16 + lr;
                const float bv = bff[col];
                float* obase = out + ((size_t)b * NTOK + n0 + nr) * E;
                obase[0 * E + col] = acc[0] + bv;
                obase[1 * E + col] = acc[1] + bv;
                obase[2 * E + col] = acc[2] + bv;
                obase[3 * E + col] = acc[3] + bv;
            }
        }
    }
}

extern "C" void kernel_launch(void* const* d_in, const int* in_sizes, int n_in,
                              void* d_out, int out_size, void* d_ws, size_t ws_size,
                              hipStream_t stream) {
    const float* x    = (const float*)d_in[0];
    const float* Wqkv = (const float*)d_in[1];
    const float* bqkv = (const float*)d_in[2];
    const float* Wff  = (const float*)d_in[3];
    const float* bff  = (const float*)d_in[4];
    float* out = (float*)d_out;
    short* Mp  = (short*)d_ws;                     // BB*64*MSZ bf16 partials

    k_kv<<<BB * 64, 512, 0, stream>>>(x, Wqkv, bqkv, Mp);
    k_out<<<BB * 64, 512, 0, stream>>>(x, Wqkv, bqkv, Wff, bff, Mp, out);
}